// Round 4
// baseline (811.672 us; speedup 1.0000x reference)
//
#include <hip/hip_runtime.h>
#include <hip/hip_bf16.h>
#include <math.h>

// Problem constants (B=2, L=1024 -> T=2048 tokens)
#define T_TOK 2048
#define Dd    2048
#define Ee    8
#define Hh    1408
#define HSs   2816
#define CAP   1024   // per-expert capacity (mean 512, ~24 sigma headroom)

typedef __attribute__((ext_vector_type(8))) __bf16 bf16x8;
typedef __attribute__((ext_vector_type(4))) __bf16 bf16x4;
typedef __attribute__((ext_vector_type(2))) __bf16 bf16x2;
typedef __attribute__((ext_vector_type(4))) float  f32x4;

#define MFMA(a, b, c) __builtin_amdgcn_mfma_f32_16x16x32_bf16(a, b, c, 0, 0, 0)

// async global->LDS 16B/lane (LDS dest = wave-uniform base + lane*16)
__device__ __forceinline__ void async_copy16(const __bf16* g, __bf16* l) {
    __builtin_amdgcn_global_load_lds(
        (const __attribute__((address_space(1))) unsigned int*)g,
        (__attribute__((address_space(3))) unsigned int*)l, 16, 0, 0);
}

// ---------------------------------------------------------------------------
__global__ void init_cnt(int* __restrict__ cnt) {
    if (threadIdx.x < Ee) cnt[threadIdx.x] = 0;
}

// ---------------------------------------------------------------------------
// router: logits, top-2 renorm weights, packed per-expert lists (token, slot,
// weight), shared-expert sigmoid gate
// ---------------------------------------------------------------------------
__global__ __launch_bounds__(256) void router_kernel(
    const float* __restrict__ x, const float* __restrict__ gate_w,
    const float* __restrict__ shgate_w,
    int* __restrict__ cnt, int* __restrict__ ptok, int* __restrict__ pslot,
    float* __restrict__ pw, float* __restrict__ sgate)
{
    const int t = blockIdx.x;
    const int tid = threadIdx.x;
    const float* xt = x + (size_t)t * Dd;

    float acc[Ee];
#pragma unroll
    for (int e = 0; e < Ee; e++) acc[e] = 0.f;
    float accs = 0.f;

    for (int d = tid; d < Dd; d += 256) {
        float xv = xt[d];
#pragma unroll
        for (int e = 0; e < Ee; e++) acc[e] += xv * gate_w[e * Dd + d];
        accs += xv * shgate_w[d];
    }

    __shared__ float red[Ee + 1][256];
#pragma unroll
    for (int e = 0; e < Ee; e++) red[e][tid] = acc[e];
    red[Ee][tid] = accs;
    __syncthreads();

    for (int s = 128; s > 0; s >>= 1) {
        if (tid < s) {
#pragma unroll
            for (int e = 0; e <= Ee; e++) red[e][tid] += red[e][tid + s];
        }
        __syncthreads();
    }

    if (tid == 0) {
        float l0 = -1e30f, l1 = -1e30f;
        int i0 = 0, i1 = 0;
#pragma unroll
        for (int e = 0; e < Ee; e++) {
            float v = red[e][0];
            if (v > l0) { l1 = l0; i1 = i0; l0 = v; i0 = e; }
            else if (v > l1) { l1 = v; i1 = e; }
        }
        float w0 = 1.f / (1.f + expf(l1 - l0));  // renormalized top-2
        float w1 = 1.f - w0;

        int p0 = atomicAdd(&cnt[i0], 1);
        if (p0 < CAP) {
            ptok[i0 * CAP + p0] = t; pslot[i0 * CAP + p0] = 2 * t;
            pw[i0 * CAP + p0] = w0;
        }
        int p1 = atomicAdd(&cnt[i1], 1);
        if (p1 < CAP) {
            ptok[i1 * CAP + p1] = t; pslot[i1 * CAP + p1] = 2 * t + 1;
            pw[i1 * CAP + p1] = w1;
        }
        sgate[t] = 1.f / (1.f + expf(-red[Ee][0]));
    }
}

// ---------------------------------------------------------------------------
// cvt_x: fp32 -> bf16 copy of x
// ---------------------------------------------------------------------------
__global__ __launch_bounds__(256) void cvt_x(const float* __restrict__ src,
                                             __bf16* __restrict__ dst)
{
    int i = blockIdx.x * 256 + threadIdx.x;  // i < T*D/4
    float4 v = ((const float4*)src)[i];
    bf16x4 o = { (__bf16)v.x, (__bf16)v.y, (__bf16)v.z, (__bf16)v.w };
    ((bf16x4*)dst)[i] = o;
}

// ---------------------------------------------------------------------------
// transpose_cvt: src fp32 [R][C] (batched) -> dst bf16 [C][R]
// 64x64 tiles, 256 threads.
// Store phase (FIXED from round 3): half-wave of 32 lanes writes one dst
// column (64 rows) as 32 bf16x2 pairs; 8 columns/iter x 8 iters = 64 cols.
// ---------------------------------------------------------------------------
__global__ __launch_bounds__(256) void transpose_cvt(
    const float* __restrict__ src, __bf16* __restrict__ dst, int R, int C)
{
    src += (size_t)blockIdx.z * R * C;
    dst += (size_t)blockIdx.z * R * C;
    __shared__ float tile[64][65];
    const int tid = threadIdx.x, tx = tid & 63, ty = tid >> 6;
    const int c0 = blockIdx.x * 64, r0 = blockIdx.y * 64;
#pragma unroll
    for (int j = 0; j < 16; j++) {
        int r = j * 4 + ty;
        tile[r][tx] = src[(size_t)(r0 + r) * C + c0 + tx];
    }
    __syncthreads();
    const int rp = (tid & 31) * 2;      // row pair 0..62
    const int cg = tid >> 5;            // column group 0..7
#pragma unroll
    for (int j = 0; j < 8; j++) {
        int c = j * 8 + cg;
        bf16x2 v = { (__bf16)tile[rp][c], (__bf16)tile[rp + 1][c] };
        *(bf16x2*)&dst[(size_t)(c0 + c) * R + r0 + rp] = v;
    }
}

// ---------------------------------------------------------------------------
// gateup_all: merged expert + shared gate/up GEMM.
//   C[128 rows x 64 h] for gate AND up; silu(g)*u fused via LDS exchange.
//   Fragment-linear LDS: frag load = base + lane*16B (conflict-free).
//   Waves 2x2: wr = row half (64 rows), wc = 0 -> gate, 1 -> up.
// grid.x = 1408 (expert: (e*8+mt)*22+ht) + 704 (shared: mt*44+ht)
// ---------------------------------------------------------------------------
__global__ __launch_bounds__(256, 3) void gateup_all(
    const __bf16* __restrict__ xb,
    const __bf16* __restrict__ wgT, const __bf16* __restrict__ wuT,
    const __bf16* __restrict__ shwgT, const __bf16* __restrict__ shwuT,
    const int* __restrict__ cnt, const int* __restrict__ ptok,
    __bf16* __restrict__ hq, __bf16* __restrict__ shh)
{
    const int bx = blockIdx.x;
    const int tid = threadIdx.x, lane = tid & 63, wave = tid >> 6;
    const int wr = wave >> 1, wc = wave & 1;
    const int lm = lane & 15, lq = lane >> 4;

    bool sh;
    int m0, h0, n, e = 0;
    const __bf16 *bg_mat, *bu_mat;
    if (bx < 1408) {
        sh = false;
        int mtg = bx / 22, ht = bx - mtg * 22;
        e = mtg >> 3; m0 = (mtg & 7) * 128; h0 = ht * 64;
        n = cnt[e]; if (n > CAP) n = CAP;
        if (m0 >= n) return;
        bg_mat = wgT + (size_t)e * Hh * Dd;
        bu_mat = wuT + (size_t)e * Hh * Dd;
    } else {
        sh = true;
        int s = bx - 1408;
        int mt = s / 44, ht = s - mt * 44;
        m0 = mt * 128; h0 = ht * 64; n = T_TOK;
        bg_mat = shwgT; bu_mat = shwuT;
    }

    // stage: A fblocks 0..7 @ [0,4096), Bg fb 0..3 @ [4096,6144), Bu @ [6144,8192)
    __shared__ __align__(16) __bf16 stage[8192];
    __shared__ int tok_s[128];

    if (tid < 128) {
        int i = m0 + tid;
        if (sh) tok_s[tid] = i;
        else { int ic = i < n ? i : n - 1; tok_s[tid] = ptok[e * CAP + ic]; }
    }
    __syncthreads();

    // staging: wave stages A fb {wave, 4+wave}, Bg fb wave, Bu fb wave.
    // lane (lm,lq) loads row (16*fb+lm), k-chunk lq -> LDS in frag order.
    const __bf16* pa0 = xb + (size_t)tok_s[wave * 16 + lm] * Dd + lq * 8;
    const __bf16* pa1 = xb + (size_t)tok_s[64 + wave * 16 + lm] * Dd + lq * 8;
    const __bf16* pbg = bg_mat + (size_t)(h0 + wave * 16 + lm) * Dd + lq * 8;
    const __bf16* pbu = bu_mat + (size_t)(h0 + wave * 16 + lm) * Dd + lq * 8;
    __bf16* la0 = stage + wave * 512 + lane * 8;
    __bf16* la1 = stage + (4 + wave) * 512 + lane * 8;
    __bf16* lbg = stage + 4096 + wave * 512 + lane * 8;
    __bf16* lbu = stage + 6144 + wave * 512 + lane * 8;

    f32x4 acc[4][4] = {};

    for (int k0 = 0; k0 < Dd; k0 += 32) {
        async_copy16(pa0, la0); async_copy16(pa1, la1);
        async_copy16(pbg, lbg); async_copy16(pbu, lbu);
        pa0 += 32; pa1 += 32; pbg += 32; pbu += 32;
        __syncthreads();
        bf16x8 af[4], bfr[4];
        const __bf16* bbase = stage + (wc ? 6144 : 4096);
#pragma unroll
        for (int i = 0; i < 4; i++)
            af[i] = *(const bf16x8*)(stage + (wr * 4 + i) * 512 + lane * 8);
#pragma unroll
        for (int j = 0; j < 4; j++)
            bfr[j] = *(const bf16x8*)(bbase + j * 512 + lane * 8);
#pragma unroll
        for (int i = 0; i < 4; i++)
#pragma unroll
            for (int j = 0; j < 4; j++)
                acc[i][j] = MFMA(af[i], bfr[j], acc[i][j]);
        __syncthreads();
    }

    // epilogue: up waves (wc=1) publish u to LDS; gate waves fuse silu(g)*u
    if (wc == 1) {
#pragma unroll
        for (int i = 0; i < 4; i++)
#pragma unroll
            for (int j = 0; j < 4; j++) {
                bf16x4 uv;
#pragma unroll
                for (int r = 0; r < 4; r++) uv[r] = (__bf16)acc[i][j][r];
                *(bf16x4*)(stage + ((wr * 4 + i) * 4 + j) * 256 + lane * 4) = uv;
            }
    }
    __syncthreads();
    if (wc == 0) {
#pragma unroll
        for (int i = 0; i < 4; i++)
#pragma unroll
            for (int j = 0; j < 4; j++) {
                bf16x4 uv = *(const bf16x4*)(stage + ((wr * 4 + i) * 4 + j) * 256 + lane * 4);
                int col = h0 + j * 16 + lm;
#pragma unroll
                for (int r = 0; r < 4; r++) {
                    int grow = m0 + wr * 64 + i * 16 + lq * 4 + r;
                    if (!sh && grow >= n) continue;
                    float g = acc[i][j][r], u = (float)uv[r];
                    float hv = g / (1.f + __expf(-g)) * u;
                    if (sh) shh[(size_t)grow * HSs + col] = (__bf16)hv;
                    else    hq[((size_t)e * CAP + grow) * Hh + col] = (__bf16)hv;
                }
            }
    }
}

// ---------------------------------------------------------------------------
// down_all: merged expert + shared down GEMM, 128x128 tile, frag-linear LDS.
//   expert: eo[slot][d] = w * (hq_row @ w_down)   (plain store, no atomics)
//   shared: out[t][d]   = sgate[t] * (shh_row @ shw_down)
// grid.x = 1024 (expert: e<<7 | mt<<4 | nt) + 256 (shared: mt<<4 | nt)
// ---------------------------------------------------------------------------
__global__ __launch_bounds__(256, 3) void down_all(
    const __bf16* __restrict__ hq, const __bf16* __restrict__ wdT,
    const __bf16* __restrict__ shh, const __bf16* __restrict__ shwdT,
    const int* __restrict__ cnt, const int* __restrict__ pslot,
    const float* __restrict__ pw, const float* __restrict__ sgate,
    float* __restrict__ eo, float* __restrict__ out)
{
    const int bx = blockIdx.x;
    const int tid = threadIdx.x, lane = tid & 63, wave = tid >> 6;
    const int wr = wave >> 1, wc = wave & 1;
    const int lm = lane & 15, lq = lane >> 4;

    bool sh;
    int m0, n0, n, e = 0, kdim;
    if (bx < 1024) {
        sh = false;
        e = bx >> 7; m0 = ((bx >> 4) & 7) * 128; n0 = (bx & 15) * 128;
        n = cnt[e]; if (n > CAP) n = CAP;
        if (m0 >= n) return;
        kdim = Hh;
    } else {
        sh = true;
        int s = bx - 1024;
        m0 = (s >> 4) * 128; n0 = (s & 15) * 128; n = T_TOK;
        kdim = HSs;
    }

    __shared__ __align__(16) __bf16 stage[8192];  // A @ [0,4096), B @ [4096,8192)
    __shared__ int   slot_s[128];
    __shared__ float w_s[128];

    if (!sh && tid < 128) {
        int i = m0 + tid; int ic = i < n ? i : n - 1;
        slot_s[tid] = pslot[e * CAP + ic];
        w_s[tid] = (i < n) ? pw[e * CAP + ic] : 0.f;
    }

    int ar0 = m0 + wave * 16 + lm, ar1 = m0 + 64 + wave * 16 + lm;
    const __bf16 *pa0, *pa1, *pb0, *pb1;
    if (sh) {
        pa0 = shh + (size_t)ar0 * HSs + lq * 8;
        pa1 = shh + (size_t)ar1 * HSs + lq * 8;
        pb0 = shwdT + (size_t)(n0 + wave * 16 + lm) * HSs + lq * 8;
        pb1 = shwdT + (size_t)(n0 + 64 + wave * 16 + lm) * HSs + lq * 8;
    } else {
        int a0c = ar0 < n ? ar0 : n - 1;
        int a1c = ar1 < n ? ar1 : n - 1;
        pa0 = hq + ((size_t)e * CAP + a0c) * Hh + lq * 8;
        pa1 = hq + ((size_t)e * CAP + a1c) * Hh + lq * 8;
        pb0 = wdT + ((size_t)e * Dd + n0 + wave * 16 + lm) * Hh + lq * 8;
        pb1 = wdT + ((size_t)e * Dd + n0 + 64 + wave * 16 + lm) * Hh + lq * 8;
    }
    __bf16* la0 = stage + wave * 512 + lane * 8;
    __bf16* la1 = stage + (4 + wave) * 512 + lane * 8;
    __bf16* lb0 = stage + 4096 + wave * 512 + lane * 8;
    __bf16* lb1 = stage + 4096 + (4 + wave) * 512 + lane * 8;

    f32x4 acc[4][4] = {};

    for (int k0 = 0; k0 < kdim; k0 += 32) {
        async_copy16(pa0, la0); async_copy16(pa1, la1);
        async_copy16(pb0, lb0); async_copy16(pb1, lb1);
        pa0 += 32; pa1 += 32; pb0 += 32; pb1 += 32;
        __syncthreads();
        bf16x8 af[4], bfr[4];
#pragma unroll
        for (int i = 0; i < 4; i++)
            af[i] = *(const bf16x8*)(stage + (wr * 4 + i) * 512 + lane * 8);
#pragma unroll
        for (int j = 0; j < 4; j++)
            bfr[j] = *(const bf16x8*)(stage + 4096 + (wc * 4 + j) * 512 + lane * 8);
#pragma unroll
        for (int i = 0; i < 4; i++)
#pragma unroll
            for (int j = 0; j < 4; j++)
                acc[i][j] = MFMA(af[i], bfr[j], acc[i][j]);
        __syncthreads();
    }

#pragma unroll
    for (int i = 0; i < 4; i++)
#pragma unroll
        for (int r = 0; r < 4; r++) {
            int rloc = wr * 64 + i * 16 + lq * 4 + r;
            if (sh) {
                int t = m0 + rloc;
                float sg = sgate[t];
#pragma unroll
                for (int j = 0; j < 4; j++)
                    out[(size_t)t * Dd + n0 + (wc * 4 + j) * 16 + lm] = sg * acc[i][j][r];
            } else if (m0 + rloc < n) {
                int   slot = slot_s[rloc];
                float w    = w_s[rloc];
#pragma unroll
                for (int j = 0; j < 4; j++)
                    eo[(size_t)slot * Dd + n0 + (wc * 4 + j) * 16 + lm] = w * acc[i][j][r];
            }
        }
}

// ---------------------------------------------------------------------------
// combine: out[t] += eo[2t] + eo[2t+1]   (weights already applied)
// ---------------------------------------------------------------------------
__global__ __launch_bounds__(256) void combine_kernel(
    const float* __restrict__ eo, float* __restrict__ out)
{
    int i4 = blockIdx.x * 256 + threadIdx.x;   // over T*Dd/4
    int t = i4 >> 9;                            // Dd/4 = 512
    int c = i4 & 511;
    float4 o = ((const float4*)out)[i4];
    float4 a = ((const float4*)(eo + (size_t)(2 * t) * Dd))[c];
    float4 b = ((const float4*)(eo + (size_t)(2 * t + 1) * Dd))[c];
    o.x += a.x + b.x; o.y += a.y + b.y; o.z += a.z + b.z; o.w += a.w + b.w;
    ((float4*)out)[i4] = o;
}

// ---------------------------------------------------------------------------
// launch
// ---------------------------------------------------------------------------
extern "C" void kernel_launch(void* const* d_in, const int* in_sizes, int n_in,
                              void* d_out, int out_size, void* d_ws, size_t ws_size,
                              hipStream_t stream) {
    const float* x        = (const float*)d_in[0];
    const float* gate_w   = (const float*)d_in[1];
    const float* w_gate   = (const float*)d_in[2];
    const float* w_up     = (const float*)d_in[3];
    const float* w_down   = (const float*)d_in[4];
    const float* shgate_w = (const float*)d_in[5];
    const float* shw_gate = (const float*)d_in[6];
    const float* shw_up   = (const float*)d_in[7];
    const float* shw_down = (const float*)d_in[8];
    float* out = (float*)d_out;

    char* ws = (char*)d_ws;
    size_t off = 0;
    auto alloc = [&](size_t bytes) { char* p = ws + off; off = (off + bytes + 255) & ~(size_t)255; return p; };
    int*    cnt    = (int*)   alloc(Ee * 4);
    int*    ptok   = (int*)   alloc(Ee * CAP * 4);
    int*    pslot  = (int*)   alloc(Ee * CAP * 4);
    float*  pw     = (float*) alloc(Ee * CAP * 4);
    float*  sgate  = (float*) alloc(T_TOK * 4);
    __bf16* xb     = (__bf16*)alloc((size_t)T_TOK * Dd * 2);
    __bf16* wgT    = (__bf16*)alloc((size_t)Ee * Hh * Dd * 2);
    __bf16* wuT    = (__bf16*)alloc((size_t)Ee * Hh * Dd * 2);
    __bf16* wdT    = (__bf16*)alloc((size_t)Ee * Dd * Hh * 2);
    __bf16* shwgT  = (__bf16*)alloc((size_t)HSs * Dd * 2);
    __bf16* shwuT  = (__bf16*)alloc((size_t)HSs * Dd * 2);
    __bf16* shwdT  = (__bf16*)alloc((size_t)Dd * HSs * 2);
    __bf16* hq     = (__bf16*)alloc((size_t)Ee * CAP * Hh * 2);
    __bf16* shh    = (__bf16*)alloc((size_t)T_TOK * HSs * 2);
    float*  eo     = (float*) alloc((size_t)T_TOK * 2 * Dd * 4);

    dim3 b256(256);

    init_cnt<<<dim3(1), dim3(64), 0, stream>>>(cnt);
    router_kernel<<<dim3(T_TOK), b256, 0, stream>>>(
        x, gate_w, shgate_w, cnt, ptok, pslot, pw, sgate);
    cvt_x<<<dim3(T_TOK * Dd / 4 / 256), b256, 0, stream>>>(x, xb);
    // weight transposes: src [R][C] fp32 -> dst bf16 [C][R]
    transpose_cvt<<<dim3(Hh / 64, Dd / 64, Ee), b256, 0, stream>>>(w_gate, wgT, Dd, Hh);
    transpose_cvt<<<dim3(Hh / 64, Dd / 64, Ee), b256, 0, stream>>>(w_up, wuT, Dd, Hh);
    transpose_cvt<<<dim3(Dd / 64, Hh / 64, Ee), b256, 0, stream>>>(w_down, wdT, Hh, Dd);
    transpose_cvt<<<dim3(HSs / 64, Dd / 64, 1), b256, 0, stream>>>(shw_gate, shwgT, Dd, HSs);
    transpose_cvt<<<dim3(HSs / 64, Dd / 64, 1), b256, 0, stream>>>(shw_up, shwuT, Dd, HSs);
    transpose_cvt<<<dim3(Dd / 64, HSs / 64, 1), b256, 0, stream>>>(shw_down, shwdT, HSs, Dd);

    gateup_all<<<dim3(1408 + 704), b256, 0, stream>>>(
        xb, wgT, wuT, shwgT, shwuT, cnt, ptok, hq, shh);
    down_all<<<dim3(1024 + 256), b256, 0, stream>>>(
        hq, wdT, shh, shwdT, cnt, pslot, pw, sgate, eo, out);
    combine_kernel<<<dim3(T_TOK * Dd / 4 / 256), b256, 0, stream>>>(eo, out);
}